// Round 9
// baseline (350.505 us; speedup 1.0000x reference)
//
#include <hip/hip_runtime.h>

#define TT  8
#define NN  50000
#define EE  5000
#define NZ  100000
#define DD  128
#define ETILES ((EE + 63) / 64)   // 79
#define ECAP 64                   // max hyperedge degree stored (Poisson(20))
#define NCAP 16                   // max node degree stored (Poisson(2), P(>16)~1e-11)
#define LSTR 136                  // LDS row stride in shorts (272 B)

typedef __attribute__((ext_vector_type(8))) short short8v;
typedef __attribute__((ext_vector_type(4))) float float4v;

__device__ __forceinline__ unsigned short f2bf(float f) {
    return __builtin_bit_cast(unsigned short, (__bf16)f);
}
__device__ __forceinline__ float bf2f(unsigned short u) {
    return (float)__builtin_bit_cast(__bf16, u);
}
__device__ __forceinline__ unsigned short f2h(float f) {
    return __builtin_bit_cast(unsigned short, (_Float16)f);
}
__device__ __forceinline__ float h2f(unsigned short u) {
    return (float)__builtin_bit_cast(_Float16, u);
}

// ---------------- ELL build ----------------
__global__ __launch_bounds__(256) void k_build(const int* __restrict__ pn, const int* __restrict__ pe,
                                               int* __restrict__ dvcnt, int* __restrict__ decnt,
                                               int* __restrict__ ell_e, int* __restrict__ ell_n) {
    const int t = blockIdx.x & 7;
    const int i = (blockIdx.x >> 3) * 256 + threadIdx.x;
    if (i >= NZ) return;
    int n = pn[(size_t)t * NZ + i];
    int e = pe[(size_t)t * NZ + i];
    int se_ = atomicAdd(&decnt[(size_t)t * EE + e], 1);
    if (se_ < ECAP) ell_e[((size_t)t * EE + e) * ECAP + se_] = n;
    int sn = atomicAdd(&dvcnt[(size_t)t * NN + n], 1);
    if (sn < NCAP) ell_n[((size_t)t * NN + n) * NCAP + sn] = e;
}

// ---------------- degree finalize ----------------
__global__ __launch_bounds__(256) void k_fin(const int* __restrict__ dvcnt, const int* __restrict__ decnt,
                                             float* __restrict__ dvis, float* __restrict__ deinv) {
    int i = blockIdx.x * 256 + threadIdx.x;
    if (i < TT * NN) {
        int c = dvcnt[i];
        dvis[i] = (c > 0) ? rsqrtf((float)c) : 0.0f;
    } else {
        int j = i - TT * NN;
        if (j < TT * EE) {
            int c = decnt[j];
            deinv[j] = (c > 0) ? 1.0f / (float)c : 0.0f;
        }
    }
}

// ---------------- W fragment precompute (hi/lo bf16, MFMA fragment-major) ----------------
__global__ __launch_bounds__(256) void k_prepw(const float* __restrict__ W0, const float* __restrict__ W1,
                                               unsigned short* __restrict__ fragH,
                                               unsigned short* __restrict__ fragL) {
    const float* W = blockIdx.x ? W1 : W0;
    unsigned short* fh = fragH + (size_t)blockIdx.x * 16384;
    unsigned short* fl = fragL + (size_t)blockIdx.x * 16384;
    const int wave = threadIdx.x >> 6, lane = threadIdx.x & 63;
    const int l15 = lane & 15, l4 = lane >> 4;
    #pragma unroll
    for (int c = 0; c < 2; c++)
        #pragma unroll
        for (int s = 0; s < 4; s++)
            #pragma unroll
            for (int j = 0; j < 8; j++) {
                float wv = W[(size_t)(s * 32 + l4 * 8 + j) * DD + wave * 32 + c * 16 + l15];
                unsigned short h = f2bf(wv);
                int idx = (((wave * 2 + c) * 4 + s) * 64 + lane) * 8 + j;
                fh[idx] = h;
                fl[idx] = f2bf(wv - bf2f(h));
            }
}

// ---------------- cast: xh[n,d] = fp16(dvis[n] * x[n,d])  (streaming, coalesced) ----------------
__global__ __launch_bounds__(256) void k_cast(const float* __restrict__ x, const float* __restrict__ dvis,
                                              unsigned short* __restrict__ xh) {
    int gid = blockIdx.x * 256 + threadIdx.x;          // one thread per 8 elements
    if (gid >= TT * NN * (DD / 8)) return;
    int row = gid >> 4;                                 // composite t*NN+n
    int c8 = gid & 15;
    float dv = dvis[row];
    float4 a0 = *(const float4*)(x + (size_t)row * DD + c8 * 8);
    float4 a1 = *(const float4*)(x + (size_t)row * DD + c8 * 8 + 4);
    short8v o;
    o[0] = (short)f2h(dv * a0.x); o[1] = (short)f2h(dv * a0.y);
    o[2] = (short)f2h(dv * a0.z); o[3] = (short)f2h(dv * a0.w);
    o[4] = (short)f2h(dv * a1.x); o[5] = (short)f2h(dv * a1.y);
    o[6] = (short)f2h(dv * a1.z); o[7] = (short)f2h(dv * a1.w);
    *(short8v*)(xh + (size_t)row * DD + c8 * 8) = o;
}

// ---------------- gather_eb: g[e] = sum_{n in e} xh_n (fp32 acc), se[e] = sum dvis[n] ----------------
__global__ __launch_bounds__(256) void k_gather_eb(const int* __restrict__ ell_e, const int* __restrict__ decnt,
                                                   const float* __restrict__ dvis,
                                                   const unsigned short* __restrict__ xh,
                                                   float* __restrict__ g, float* __restrict__ se) {
    const int t = blockIdx.x & 7;
    const int e = (blockIdx.x >> 3) * 16 + (threadIdx.x >> 4);
    const int lane16 = threadIdx.x & 15;
    if (e >= EE) return;
    const unsigned short* xsrc = xh + (size_t)t * NN * DD;
    const float* dvs = dvis + (size_t)t * NN;
    const int* ellrow = ell_e + ((size_t)t * EE + e) * ECAP;
    int cnt = decnt[(size_t)t * EE + e];
    cnt = cnt < ECAP ? cnt : ECAP;
    float acc[8] = {};
    float sacc = 0.f;
    for (int b = 0; b < ECAP; b += 16) {
        if (b >= cnt) break;
        int valid = (b + lane16 < cnt);
        int idx = valid ? ellrow[b + lane16] : 0;
        sacc += valid ? dvs[idx] : 0.f;
        #pragma unroll
        for (int j = 0; j < 16; j++) {
            if (b + j < cnt) {
                int n = __shfl(idx, j, 16);
                short8v v = *(const short8v*)(xsrc + (size_t)n * DD + lane16 * 8);
                #pragma unroll
                for (int k = 0; k < 8; k++) acc[k] += h2f((unsigned short)v[k]);
            }
        }
    }
    float* gout = g + ((size_t)t * EE + e) * DD;
    *(float4*)(gout + lane16 * 8)     = make_float4(acc[0], acc[1], acc[2], acc[3]);
    *(float4*)(gout + lane16 * 8 + 4) = make_float4(acc[4], acc[5], acc[6], acc[7]);
    // reduce sacc over the 16-lane group
    #pragma unroll
    for (int w = 1; w < 16; w <<= 1) sacc += __shfl_xor(sacc, w, 16);
    if (lane16 == 0) se[(size_t)t * EE + e] = sacc;
}

// ---------------- E-row GEMM: ef[e] = fp16( deinv[e]*(g[e] @ W + se[e]*b) ) ----------------
__global__ __launch_bounds__(256) void k_gemmE(const float* __restrict__ g,
                                               const float* __restrict__ se,
                                               const float* __restrict__ deinv,
                                               const unsigned short* __restrict__ fragH,
                                               const unsigned short* __restrict__ fragL,
                                               const float* __restrict__ bias,
                                               unsigned short* __restrict__ ef) {
    __shared__ unsigned short Ah[64 * LSTR];
    __shared__ unsigned short Al[64 * LSTR];
    __shared__ unsigned short E_lds[64 * LSTR];
    const int t = blockIdx.x & 7;
    const int tile = blockIdx.x >> 3;
    const int row0 = tile * 64;
    const float* gsrc = g + (size_t)t * EE * DD;
    const float* sesrc = se + (size_t)t * EE;
    const float* desrc = deinv + (size_t)t * EE;
    unsigned short* outp = ef + (size_t)t * EE * DD;
    const int tid = threadIdx.x;
    const int wave = tid >> 6, lane = tid & 63;
    const int l15 = lane & 15, l4 = lane >> 4;

    #pragma unroll
    for (int it = 0; it < 8; it++) {
        int idx = it * 256 + tid;
        int row = idx >> 5, col4 = idx & 31;
        float4 a = make_float4(0.f, 0.f, 0.f, 0.f);
        if (row0 + row < EE) a = *(const float4*)(gsrc + (size_t)(row0 + row) * DD + col4 * 4);
        unsigned short hx = f2bf(a.x), hy = f2bf(a.y), hz = f2bf(a.z), hw = f2bf(a.w);
        *(uint2*)(&Ah[row * LSTR + col4 * 4]) = make_uint2(
            (unsigned)hx | ((unsigned)hy << 16), (unsigned)hz | ((unsigned)hw << 16));
        *(uint2*)(&Al[row * LSTR + col4 * 4]) = make_uint2(
            (unsigned)f2bf(a.x - bf2f(hx)) | ((unsigned)f2bf(a.y - bf2f(hy)) << 16),
            (unsigned)f2bf(a.z - bf2f(hz)) | ((unsigned)f2bf(a.w - bf2f(hw)) << 16));
    }

    short8v wh[2][4], wl[2][4];
    #pragma unroll
    for (int c = 0; c < 2; c++)
        #pragma unroll
        for (int s = 0; s < 4; s++) {
            int base = (((wave * 2 + c) * 4 + s) * 64 + lane) * 8;
            wh[c][s] = *(const short8v*)(fragH + base);
            wl[c][s] = *(const short8v*)(fragL + base);
        }
    __syncthreads();

    float4v acc[4][2] = {};
    #pragma unroll
    for (int s = 0; s < 4; s++)
        #pragma unroll
        for (int r = 0; r < 4; r++) {
            short8v ah = *(const short8v*)(&Ah[(r * 16 + l15) * LSTR + s * 32 + l4 * 8]);
            short8v al = *(const short8v*)(&Al[(r * 16 + l15) * LSTR + s * 32 + l4 * 8]);
            #pragma unroll
            for (int c = 0; c < 2; c++) {
                acc[r][c] = __builtin_amdgcn_mfma_f32_16x16x32_bf16(ah, wh[c][s], acc[r][c], 0, 0, 0);
                acc[r][c] = __builtin_amdgcn_mfma_f32_16x16x32_bf16(al, wh[c][s], acc[r][c], 0, 0, 0);
                acc[r][c] = __builtin_amdgcn_mfma_f32_16x16x32_bf16(ah, wl[c][s], acc[r][c], 0, 0, 0);
            }
        }

    float b2[2] = { bias[wave * 32 + l15], bias[wave * 32 + 16 + l15] };
    __syncthreads();
    #pragma unroll
    for (int r = 0; r < 4; r++) {
        int rloc = r * 16 + l4 * 4;
        if (row0 + rloc < EE) {
            float4 de4 = *(const float4*)(desrc + row0 + rloc);
            float4 se4 = *(const float4*)(sesrc + row0 + rloc);
            float dev[4] = {de4.x, de4.y, de4.z, de4.w};
            float sev[4] = {se4.x, se4.y, se4.z, se4.w};
            #pragma unroll
            for (int c = 0; c < 2; c++)
                #pragma unroll
                for (int q = 0; q < 4; q++)
                    E_lds[(rloc + q) * LSTR + wave * 32 + c * 16 + l15] =
                        f2h(dev[q] * (acc[r][c][q] + sev[q] * b2[c]));
        }
    }
    __syncthreads();
    #pragma unroll
    for (int it = 0; it < 8; it++) {
        int idx = it * 256 + tid;
        int row = idx >> 5, col4 = idx & 31;
        if (row0 + row < EE) {
            unsigned u0 = *(const unsigned*)(&E_lds[row * LSTR + col4 * 4]);
            unsigned u1 = *(const unsigned*)(&E_lds[row * LSTR + col4 * 4 + 2]);
            unsigned o2[2] = {u0, u1};
            *(uint2*)(outp + (size_t)(row0 + row) * DD + col4 * 4) = *(uint2*)o2;
        }
    }
}

// ---------------- gather_ee: g2[e] = sum_{n in e} dv_n * relu(dv_n * sum_{e' in n} ef[e']) ----------------
// Double-indirect, all ef reads L2-resident (1.28 MB/XCD). Deletes the h buffer entirely.
__global__ __launch_bounds__(256) void k_gather_ee(const int* __restrict__ ell_e, const int* __restrict__ decnt,
                                                   const int* __restrict__ ell_n, const int* __restrict__ dvcnt,
                                                   const float* __restrict__ dvis,
                                                   const unsigned short* __restrict__ ef,
                                                   float* __restrict__ g2) {
    const int t = blockIdx.x & 7;
    const int e = (blockIdx.x >> 3) * 16 + (threadIdx.x >> 4);
    const int lane16 = threadIdx.x & 15;
    if (e >= EE) return;
    const unsigned short* esrc = ef + (size_t)t * EE * DD;
    const float* dvs = dvis + (size_t)t * NN;
    const int* dcnt = dvcnt + (size_t)t * NN;
    const int* elln = ell_n + (size_t)t * NN * NCAP;
    const int* ellrow = ell_e + ((size_t)t * EE + e) * ECAP;
    int cnt = decnt[(size_t)t * EE + e];
    cnt = cnt < ECAP ? cnt : ECAP;
    float gacc[8] = {};
    for (int b = 0; b < ECAP; b += 16) {
        if (b >= cnt) break;
        int valid = (b + lane16 < cnt);
        int n_l  = valid ? ellrow[b + lane16] : 0;
        float dv_l = valid ? dvs[n_l] : 0.f;
        int cn_l = valid ? dcnt[n_l] : 0;
        cn_l = cn_l < NCAP ? cn_l : NCAP;
        #pragma unroll 4
        for (int j = 0; j < 16; j++) {
            if (b + j >= cnt) break;
            int nj   = __shfl(n_l, j, 16);
            float dvn = __shfl(dv_l, j, 16);
            int cn   = __shfl(cn_l, j, 16);
            int ev = (lane16 < cn) ? elln[(size_t)nj * NCAP + lane16] : 0;
            float hacc[8] = {};
            for (int kk = 0; kk < cn; kk += 4) {
                #pragma unroll
                for (int u = 0; u < 4; u++) {
                    if (kk + u < cn) {
                        int e2 = __shfl(ev, kk + u, 16);
                        short8v v = *(const short8v*)(esrc + (size_t)e2 * DD + lane16 * 8);
                        #pragma unroll
                        for (int k = 0; k < 8; k++) hacc[k] += h2f((unsigned short)v[k]);
                    }
                }
            }
            #pragma unroll
            for (int k = 0; k < 8; k++) gacc[k] += dvn * fmaxf(dvn * hacc[k], 0.f);
        }
    }
    float* gout = g2 + ((size_t)t * EE + e) * DD;
    *(float4*)(gout + lane16 * 8)     = make_float4(gacc[0], gacc[1], gacc[2], gacc[3]);
    *(float4*)(gout + lane16 * 8 + 4) = make_float4(gacc[4], gacc[5], gacc[6], gacc[7]);
}

// ---------------- gather_n1: fused relu + mean-pool (ef fp16, L2-resident) ----------------
__global__ __launch_bounds__(256) void k_gather_n1(const int* __restrict__ ell_n, const int* __restrict__ dvcnt,
                                                   const unsigned short* __restrict__ ef,
                                                   const float* __restrict__ dvis,
                                                   float* __restrict__ outp) {
    const int t = blockIdx.x & 7;
    const int nbase = (blockIdx.x >> 3) * 128 + (threadIdx.x >> 4) * 8;
    const int gg_ = threadIdx.x >> 4;
    const int lane16 = threadIdx.x & 15;
    const unsigned short* esrc = ef + (size_t)t * EE * DD;
    float px[8] = {};
    #pragma unroll
    for (int i = 0; i < 8; i++) {
        int n = nbase + i;
        if (n < NN) {
            const int* ellrow = ell_n + ((size_t)t * NN + n) * NCAP;
            int cnt = dvcnt[(size_t)t * NN + n];
            cnt = cnt < NCAP ? cnt : NCAP;
            float dvn = dvis[(size_t)t * NN + n];
            float acc[8] = {};
            int idx = (lane16 < cnt) ? ellrow[lane16] : 0;
            #pragma unroll
            for (int j = 0; j < 16; j++) {
                if (j < cnt) {
                    int e = __shfl(idx, j, 16);
                    short8v v = *(const short8v*)(esrc + (size_t)e * DD + lane16 * 8);
                    #pragma unroll
                    for (int k = 0; k < 8; k++) acc[k] += h2f((unsigned short)v[k]);
                }
            }
            #pragma unroll
            for (int k = 0; k < 8; k++) px[k] += fmaxf(acc[k] * dvn, 0.f);
        }
    }
    __shared__ float sp[16][128];
    #pragma unroll
    for (int k = 0; k < 8; k++) sp[gg_][lane16 * 8 + k] = px[k];
    __syncthreads();
    if (threadIdx.x < 128) {
        float ssum = 0.f;
        #pragma unroll
        for (int q = 0; q < 16; q++) ssum += sp[q][threadIdx.x];
        atomicAdd(outp + (size_t)t * DD + threadIdx.x, ssum * (1.0f / (float)NN));
    }
}

extern "C" void kernel_launch(void* const* d_in, const int* in_sizes, int n_in,
                              void* d_out, int out_size, void* d_ws, size_t ws_size,
                              hipStream_t stream) {
    const float* x  = (const float*)d_in[0];
    const float* W0 = (const float*)d_in[1];
    const float* b0 = (const float*)d_in[2];
    const float* W1 = (const float*)d_in[3];
    const float* b1 = (const float*)d_in[4];
    const int*   pn = (const int*)d_in[5];
    const int*   pe = (const int*)d_in[6];
    float* out = (float*)d_out;

    char* p = (char*)d_ws;
    auto alloc = [&](size_t bytes) -> char* {
        char* r = p;
        p += (bytes + 255) / 256 * 256;
        return r;
    };
    float* dvis  = (float*)alloc((size_t)TT * NN * 4);
    float* deinv = (float*)alloc((size_t)TT * EE * 4);
    int*   dvcnt = (int*)alloc((size_t)TT * (NN + EE) * 4);   // dvcnt then decnt
    int*   decnt = dvcnt + (size_t)TT * NN;
    int*   ell_e = (int*)alloc((size_t)TT * EE * ECAP * 4);   // 10.2 MB
    int*   ell_n = (int*)alloc((size_t)TT * NN * NCAP * 4);   // 25.6 MB
    unsigned short* wfragH = (unsigned short*)alloc(2 * 16384 * 2);
    unsigned short* wfragL = (unsigned short*)alloc(2 * 16384 * 2);
    unsigned short* xh = (unsigned short*)alloc((size_t)TT * NN * DD * 2);  // 102.4 MB
    float* gbuf = (float*)alloc((size_t)TT * EE * DD * 4);    // 20.5 MB (g / g2)
    float* sebuf = (float*)alloc((size_t)TT * EE * 4);
    unsigned short* ef = (unsigned short*)alloc((size_t)TT * EE * DD * 2);  // 10.2 MB (ef / ef2)

    hipMemsetAsync(dvcnt, 0, (size_t)TT * (NN + EE) * 4, stream);
    hipMemsetAsync(d_out, 0, (size_t)out_size * 4, stream);

    k_prepw<<<2, 256, 0, stream>>>(W0, W1, wfragH, wfragL);
    k_build<<<((NZ + 255) / 256) * 8, 256, 0, stream>>>(pn, pe, dvcnt, decnt, ell_e, ell_n);
    k_fin<<<(TT * (NN + EE) + 255) / 256, 256, 0, stream>>>(dvcnt, decnt, dvis, deinv);
    k_cast<<<(TT * NN * (DD / 8) + 255) / 256, 256, 0, stream>>>(x, dvis, xh);

    const dim3 ge(((EE + 15) / 16) * 8);

    // layer 0
    k_gather_eb<<<ge, 256, 0, stream>>>(ell_e, decnt, dvis, xh, gbuf, sebuf);
    k_gemmE<<<ETILES * 8, 256, 0, stream>>>(gbuf, sebuf, deinv, wfragH, wfragL, b0, ef);
    // layer 1 (h fused away)
    k_gather_ee<<<ge, 256, 0, stream>>>(ell_e, decnt, ell_n, dvcnt, dvis, ef, gbuf);
    k_gemmE<<<ETILES * 8, 256, 0, stream>>>(gbuf, sebuf, deinv, wfragH + 16384, wfragL + 16384, b1, ef);
    k_gather_n1<<<((NN + 127) / 128) * 8, 256, 0, stream>>>(ell_n, dvcnt, ef, dvis, out);
}